// Round 9
// baseline (141.700 us; speedup 1.0000x reference)
//
#include <hip/hip_runtime.h>
#include <cstdint>
#include <cstddef>

#define S_CELLS 4096   // 64*64
#define NB      8
#define NPTS    8192
#define E       128
#define MAXP    20
#define NHEADS  8
#define NPT_ROWS 65536
#define NGR_ROWS 32768

// ws layout (bytes):
#define WS_COUNTS 0          // int[32768]        (131072)
#define WS_SLOTS  131072     // int[32768*20]     (2621440)
#define WS_WT1    2752512    // bf16 144x136      (40960 w/ pad)
#define WS_WT2    2793472    // bf16 128x136      (34816)
#define WS_SC     2828288    // float[98304*8]    (3145728)
#define WS_V      5974016    // bf16[98304*128]   (25165824)

typedef __attribute__((ext_vector_type(8))) short bf16x8;
typedef __attribute__((ext_vector_type(4))) float f32x4;
typedef __attribute__((ext_vector_type(2))) unsigned uint2v;

__device__ __forceinline__ unsigned short f2bf_bits(float f) {   // RNE (cold paths)
    unsigned u = __float_as_uint(f);
    unsigned rounded = u + 0x7FFFu + ((u >> 16) & 1u);
    return (unsigned short)(rounded >> 16);
}
__device__ __forceinline__ unsigned pack_bf2(float a, float b) { // [b|a], ties-away
    unsigned ua = __float_as_uint(a) + 0x8000u;
    unsigned ub = __float_as_uint(b) + 0x8000u;
    return (ua >> 16) | (ub & 0xFFFF0000u);
}
__device__ __forceinline__ float bf2f(unsigned short u) {
    return __uint_as_float(((unsigned)u) << 16);
}

// ---------------------------------------------------------------------------
// Kernel 1 (9 blocks x 256): zero counts (striped) +
//   block 0    : q = latent@Wq; A[i][h]=(Wk[i,h*16:+16].q_h)/4 -> WT1 rows
//                128..135; zero rows 136..143
//   blocks 1..4: Wv -> WT1 rows 0..127 (bf16, transposed [n][k], stride 136)
//   blocks 5..8: Wo -> WT2 (same layout)
// ---------------------------------------------------------------------------
__global__ void __launch_bounds__(256)
k_prep(const float* __restrict__ latent,
       const float* __restrict__ Wq,
       const float* __restrict__ Wk,
       const float* __restrict__ Wv,
       const float* __restrict__ Wo,
       int* __restrict__ counts,
       unsigned short* __restrict__ WT1,
       unsigned short* __restrict__ WT2) {
    const int t   = threadIdx.x;
    const int blk = blockIdx.x;

    {   // zero counts: 8192 int4s across 9*256 threads
        int4* c4 = (int4*)counts;
        for (int idx = blk * 256 + t; idx < 8192; idx += 9 * 256)
            c4[idx] = int4{0, 0, 0, 0};
    }

    if (blk == 0) {
        __shared__ float lat[E];
        __shared__ float qv[E];
        const int j = t & 127;
        if (t < E) lat[t] = latent[t];
        __syncthreads();
        float acc = 0.0f;                    // both halves compute identical q[j]
        for (int k2 = 0; k2 < E; ++k2) acc += lat[k2] * Wq[k2 * E + j];
        qv[j] = acc;
        __syncthreads();
        const int hb = (t >> 7) * 4;
        for (int h = hb; h < hb + 4; ++h) {
            float a = 0.0f;
            #pragma unroll
            for (int d = 0; d < 16; ++d) a += Wk[j * E + h * 16 + d] * qv[h * 16 + d];
            WT1[(size_t)(128 + h) * 136 + j] = f2bf_bits(a * 0.25f);
        }
        for (int idx = t; idx < 8 * 136; idx += 256) {   // zero rows 136..143
            int rr = idx / 136, cc = idx - rr * 136;
            WT1[(size_t)(136 + rr) * 136 + cc] = 0;
        }
        return;
    }

    // weight conversion: transpose via LDS, coalesced in and out
    const float* W = (blk < 5) ? Wv : Wo;
    unsigned short* WT = (blk < 5) ? WT1 : WT2;
    const int n0 = ((blk - 1) & 3) * 32;
    __shared__ float lbuf[128][33];
    #pragma unroll
    for (int it = 0; it < 16; ++it) {
        int k  = (t >> 5) + it * 8;
        int nl = t & 31;
        lbuf[k][nl] = W[(size_t)k * E + n0 + nl];
    }
    __syncthreads();
    for (int idx = t; idx < 32 * 136; idx += 256) {
        int nl = idx / 136, k = idx - nl * 136;
        float v = (k < 128) ? lbuf[k][nl] : 0.0f;
        WT[(size_t)(n0 + nl) * 136 + k] = f2bf_bits(v);
    }
}

// ---------------------------------------------------------------------------
// X-row fragment (fp32 -> bf16): lane (idx=lane&15, q=lane>>4) takes
// X[row][kq*32 + q*8 + j], j=0..7. Used as the MFMA B-operand (n=row).
// ---------------------------------------------------------------------------
__device__ __forceinline__ bf16x8 load_xfrag_f32(const float* __restrict__ X,
                                                 int row, int kq, int q) {
    const float4* xr = (const float4*)(X + (size_t)row * E);
    float4 lo = xr[kq * 8 + q * 2];
    float4 hi = xr[kq * 8 + q * 2 + 1];
    union { unsigned u4[4]; bf16x8 v; } cv;
    cv.u4[0] = pack_bf2(lo.x, lo.y);
    cv.u4[1] = pack_bf2(lo.z, lo.w);
    cv.u4[2] = pack_bf2(hi.x, hi.y);
    cv.u4[3] = pack_bf2(hi.z, hi.w);
    return cv.v;
}

// ---------------------------------------------------------------------------
// Kernel 2 (1024 blocks x 256):
//   blocks 0..767  : MFMA GEMM  V = [z; z_grid] @ Wv (bf16) + SC = X @ A
//   blocks 768..1023: per-point binning + x_grid passthrough copy
// GEMM uses W as the A-operand and X rows as the B-operand, so D has
//   m = output col j (4 consecutive per lane: j = jt*16 + q*4 + r) and
//   n = token row (cn) -> vectorized 8B V-stores / float4 SC-stores.
// Fragment layouts (HW-verified): A/B m|n=lane&15, k=kq*32+q*8+j;
//   C/D col(n)=lane&15, row(m)=q*4+r.
// ---------------------------------------------------------------------------
__global__ void __launch_bounds__(256)
k_main(const float* __restrict__ x,
       const float* __restrict__ x_grid,
       const float* __restrict__ Xz,
       const float* __restrict__ Xg,
       const unsigned short* __restrict__ WT1g,
       int* __restrict__ counts,
       int* __restrict__ slots,
       unsigned short* __restrict__ V,
       float* __restrict__ SC,
       float* __restrict__ out_xgrid) {
    __shared__ unsigned short W_t[20480];    // 40960 B

    const int t = threadIdx.x;

    if (blockIdx.x >= 768) {                 // ---- binning + x_grid copy
        int i = (blockIdx.x - 768) * 256 + t;   // 0..65535
        out_xgrid[i] = x_grid[i];
        int b = i >> 13;
        float x0 = x[(size_t)i * 2 + 0];
        float x1 = x[(size_t)i * 2 + 1];
        int i0 = (int)rintf(x0 * 63.0f);     // RNE matches jnp.round
        int i1 = (int)rintf(x1 * 63.0f);
        i0 = min(max(i0, 0), 63);
        i1 = min(max(i1, 0), 63);
        int cell = b * S_CELLS + i0 * 64 + i1;
        int slot = atomicAdd(&counts[cell], 1);
        if (slot < MAXP) slots[(size_t)cell * MAXP + slot] = i & (NPTS - 1);
        return;
    }

    {   // linear stage of WT1 image (no transpose -> no conflicts)
        const float4* src = (const float4*)WT1g;
        float4* dst = (float4*)W_t;
        #pragma unroll
        for (int it = 0; it < 10; ++it) dst[t + it * 256] = src[t + it * 256];
    }
    __syncthreads();

    const int lane = t & 63;
    const int wv   = t >> 6;
    const int cn   = lane & 15;
    const int q    = lane >> 4;

    const int grow0 = blockIdx.x * 128;
    const float* Xsrc;
    int srow;
    if (blockIdx.x < 512) { Xsrc = Xz; srow = grow0; }
    else                  { Xsrc = Xg; srow = grow0 - NPT_ROWS; }

    f32x4 acc[2][9];
    #pragma unroll
    for (int mt = 0; mt < 2; ++mt)
        #pragma unroll
        for (int jt = 0; jt < 9; ++jt)
            acc[mt][jt] = f32x4{0.0f, 0.0f, 0.0f, 0.0f};

    #pragma unroll
    for (int kq = 0; kq < 4; ++kq) {
        bf16x8 bx[2];
        #pragma unroll
        for (int mt = 0; mt < 2; ++mt)
            bx[mt] = load_xfrag_f32(Xsrc, srow + wv * 32 + mt * 16 + cn, kq, q);
        #pragma unroll
        for (int jt = 0; jt < 9; ++jt) {
            const bf16x8 aw = *(const bf16x8*)&W_t[(size_t)(jt * 16 + cn) * 136 + kq * 32 + q * 8];
            #pragma unroll
            for (int mt = 0; mt < 2; ++mt)
                acc[mt][jt] = __builtin_amdgcn_mfma_f32_16x16x32_bf16(
                    aw, bx[mt], acc[mt][jt], 0, 0, 0);
        }
    }

    // epilogue: lane -> row = base+cn, cols j = jt*16 + q*4 + (0..3)
    #pragma unroll
    for (int mt = 0; mt < 2; ++mt) {
        const size_t row = (size_t)(grow0 + wv * 32 + mt * 16 + cn);
        #pragma unroll
        for (int jt = 0; jt < 8; ++jt) {
            uint2v pk;
            pk.x = pack_bf2(acc[mt][jt][0], acc[mt][jt][1]);
            pk.y = pack_bf2(acc[mt][jt][2], acc[mt][jt][3]);
            *(uint2v*)&V[row * E + jt * 16 + q * 4] = pk;
        }
        if (q < 2)   // SC tile: h = q*4 + r (valid h<8)
            *(f32x4*)&SC[row * NHEADS + q * 4] = acc[mt][8];
    }
}

// ---------------------------------------------------------------------------
// Kernel 3 (2048 blocks x 1024): fused attention + Wo projection.
//   Block = 16 cells, 16 waves; wave wv gathers cell cb+wv. Lane owns cols
//   {2l,2l+1} (head h=l>>3 -> one softmax state, packed uint V loads).
//   Result -> X_s[wv] (bf16). Phase 2: waves 0..7 hold Wo A-frags (j-tile
//   jt=wv) in registers; X_s rows are the B-operand -> D n=cell(cn),
//   m=j(q*4+r) -> one float4 zg store per lane. LDS 4352 B.
// ---------------------------------------------------------------------------
__global__ void __launch_bounds__(1024)
k_attn_proj(const int* __restrict__ counts,
            const int* __restrict__ slots,
            const float* __restrict__ SC,
            const unsigned short* __restrict__ Vg,
            const unsigned short* __restrict__ WT2g,
            float* __restrict__ zg) {
    __shared__ __align__(16) unsigned short X_s[16][136];

    const int t    = threadIdx.x;
    const int lane = t & 63;
    const int wv   = t >> 6;                 // 0..15
    const int cb   = blockIdx.x * 16;
    const int b    = cb >> 12;
    const int base = b * NPTS;
    const int cn   = lane & 15;
    const int q    = lane >> 4;

    // preload Wo A-fragments (j-tile = wv for waves 0..7) — independent of phase 1
    bf16x8 afr[4];
    if (wv < 8) {
        #pragma unroll
        for (int kq = 0; kq < 4; ++kq)
            afr[kq] = *(const bf16x8*)&WT2g[(size_t)(wv * 16 + cn) * 136 + kq * 32 + q * 8];
    }

    // ---- phase 1: gather + online softmax for cell cb+wv
    const int cell = cb + wv;
    const int m    = min(counts[cell], MAXP);          // wave-uniform broadcast
    int sl = (lane < MAXP) ? slots[(size_t)cell * MAXP + lane] : 0;
    const int h = lane >> 3;

    size_t r0 = (size_t)(NPT_ROWS + cell);
    float mm = SC[r0 * NHEADS + h];
    float ss = 1.0f;
    unsigned v0 = *(const unsigned*)(Vg + r0 * E + 2 * lane);
    float o0 = bf2f((unsigned short)v0);
    float o1 = bf2f((unsigned short)(v0 >> 16));

    for (int t0 = 0; t0 < m; t0 += 4) {
        float av[4], p0[4], p1[4];
        #pragma unroll
        for (int j = 0; j < 4; ++j) {
            int pt = __shfl(sl, t0 + j, 64);
            bool val = (t0 + j) < m;
            pt = val ? pt : 0;               // slots beyond m are garbage
            size_t r = (size_t)(base + pt);
            float sa = SC[r * NHEADS + h];
            av[j] = val ? sa : -1e30f;       // masked -> e=0, alpha=1: exact no-op
            unsigned vv = *(const unsigned*)(Vg + r * E + 2 * lane);
            p0[j] = bf2f((unsigned short)vv);
            p1[j] = bf2f((unsigned short)(vv >> 16));
        }
        #pragma unroll
        for (int j = 0; j < 4; ++j) {
            float nm = fmaxf(mm, av[j]);
            float e  = __expf(av[j] - nm);
            float al = __expf(mm - nm);
            ss = ss * al + e;
            o0 = o0 * al + e * p0[j];
            o1 = o1 * al + e * p1[j];
            mm = nm;
        }
    }
    float inv = 1.0f / ss;
    *(unsigned*)&X_s[wv][2 * lane] = pack_bf2(o0 * inv, o1 * inv);
    __syncthreads();

    // ---- phase 2: zg[cb..cb+15][:] = X_s @ Wo  (wave wv -> j-tile jt=wv)
    if (wv < 8) {
        f32x4 acc = f32x4{0.0f, 0.0f, 0.0f, 0.0f};
        #pragma unroll
        for (int kq = 0; kq < 4; ++kq) {
            bf16x8 bx = *(const bf16x8*)&X_s[cn][kq * 32 + q * 8];
            acc = __builtin_amdgcn_mfma_f32_16x16x32_bf16(afr[kq], bx, acc, 0, 0, 0);
        }
        // D: n=cell(cn), m=j(q*4+r) -> contiguous float4
        *(f32x4*)&zg[(size_t)(cb + cn) * E + wv * 16 + q * 4] = acc;
    }
}

// ---------------------------------------------------------------------------
extern "C" void kernel_launch(void* const* d_in, const int* in_sizes, int n_in,
                              void* d_out, int out_size, void* d_ws, size_t ws_size,
                              hipStream_t stream) {
    const float* x      = (const float*)d_in[0];
    const float* z      = (const float*)d_in[1];
    const float* x_grid = (const float*)d_in[2];
    const float* z_grid = (const float*)d_in[3];
    const float* latent = (const float*)d_in[4];
    const float* Wq     = (const float*)d_in[5];
    const float* Wk     = (const float*)d_in[6];
    const float* Wv     = (const float*)d_in[7];
    const float* Wo     = (const float*)d_in[8];

    char* ws = (char*)d_ws;
    int*            counts = (int*)(ws + WS_COUNTS);
    int*            slots  = (int*)(ws + WS_SLOTS);
    unsigned short* WT1    = (unsigned short*)(ws + WS_WT1);
    unsigned short* WT2    = (unsigned short*)(ws + WS_WT2);
    float*          SC     = (float*)(ws + WS_SC);
    unsigned short* V      = (unsigned short*)(ws + WS_V);

    float* out_xgrid = (float*)d_out;                  // 65536 floats
    float* zg        = (float*)d_out + NB * NPTS;      // 32768*128 floats

    k_prep<<<9, 256, 0, stream>>>(latent, Wq, Wk, Wv, Wo, counts, WT1, WT2);

    k_main<<<1024, 256, 0, stream>>>(x, x_grid, z, z_grid, WT1,
                                     counts, slots, V, SC, out_xgrid);

    k_attn_proj<<<2048, 1024, 0, stream>>>(counts, slots, SC, V, WT2, zg);
}

// Round 10
// 138.392 us; speedup vs baseline: 1.0239x; 1.0239x over previous
//
#include <hip/hip_runtime.h>
#include <cstdint>
#include <cstddef>

#define S_CELLS 4096   // 64*64
#define NB      8
#define NPTS    8192
#define E       128
#define MAXP    20
#define NHEADS  8
#define NPT_ROWS 65536
#define NGR_ROWS 32768

// ws layout (bytes):
#define WS_COUNTS 0          // int[32768]        (131072)
#define WS_SLOTS  131072     // int[32768*20]     (2621440)
#define WS_WT1    2752512    // bf16 144x136      (40960 w/ pad)
#define WS_WT2    2793472    // bf16 128x136      (34816)
#define WS_SC     2828288    // float[98304*8]    (3145728)
#define WS_V      5974016    // bf16[98304*128]   (25165824)

typedef __attribute__((ext_vector_type(8))) short bf16x8;
typedef __attribute__((ext_vector_type(4))) float f32x4;

__device__ __forceinline__ unsigned short f2bf_bits(float f) {   // RNE (cold paths)
    unsigned u = __float_as_uint(f);
    unsigned rounded = u + 0x7FFFu + ((u >> 16) & 1u);
    return (unsigned short)(rounded >> 16);
}
__device__ __forceinline__ unsigned short f2bf_rta(float f) {    // round-ties-away (hot)
    return (unsigned short)((__float_as_uint(f) + 0x8000u) >> 16);
}
__device__ __forceinline__ unsigned pack_bf2(float a, float b) { // [b|a] packed bf16
    unsigned ua = __float_as_uint(a) + 0x8000u;
    unsigned ub = __float_as_uint(b) + 0x8000u;
    return (ua >> 16) | (ub & 0xFFFF0000u);
}
__device__ __forceinline__ float bf2f(unsigned short u) {
    return __uint_as_float(((unsigned)u) << 16);
}

// ---------------------------------------------------------------------------
// Kernel 1 (9 blocks x 256): zero counts (striped) +
//   block 0    : q = latent@Wq; A[i][h]=(Wk[i,h*16:+16].q_h)/4 -> WT1 rows
//                128..135; zero rows 136..143
//   blocks 1..4: Wv -> WT1 rows 0..127 (bf16, transposed [n][k], stride 136)
//   blocks 5..8: Wo -> WT2 (same layout)
// ---------------------------------------------------------------------------
__global__ void __launch_bounds__(256)
k_prep(const float* __restrict__ latent,
       const float* __restrict__ Wq,
       const float* __restrict__ Wk,
       const float* __restrict__ Wv,
       const float* __restrict__ Wo,
       int* __restrict__ counts,
       unsigned short* __restrict__ WT1,
       unsigned short* __restrict__ WT2) {
    const int t   = threadIdx.x;
    const int blk = blockIdx.x;

    {   // zero counts: 8192 int4s across 9*256 threads
        int4* c4 = (int4*)counts;
        for (int idx = blk * 256 + t; idx < 8192; idx += 9 * 256)
            c4[idx] = int4{0, 0, 0, 0};
    }

    if (blk == 0) {
        __shared__ float lat[E];
        __shared__ float qv[E];
        const int j = t & 127;
        if (t < E) lat[t] = latent[t];
        __syncthreads();
        float acc = 0.0f;                    // both halves compute identical q[j]
        for (int k2 = 0; k2 < E; ++k2) acc += lat[k2] * Wq[k2 * E + j];
        qv[j] = acc;
        __syncthreads();
        const int hb = (t >> 7) * 4;
        for (int h = hb; h < hb + 4; ++h) {
            float a = 0.0f;
            #pragma unroll
            for (int d = 0; d < 16; ++d) a += Wk[j * E + h * 16 + d] * qv[h * 16 + d];
            WT1[(size_t)(128 + h) * 136 + j] = f2bf_bits(a * 0.25f);
        }
        for (int idx = t; idx < 8 * 136; idx += 256) {   // zero rows 136..143
            int rr = idx / 136, cc = idx - rr * 136;
            WT1[(size_t)(136 + rr) * 136 + cc] = 0;
        }
        return;
    }

    // weight conversion: transpose via LDS, coalesced in and out
    const float* W = (blk < 5) ? Wv : Wo;
    unsigned short* WT = (blk < 5) ? WT1 : WT2;
    const int n0 = ((blk - 1) & 3) * 32;
    __shared__ float lbuf[128][33];
    #pragma unroll
    for (int it = 0; it < 16; ++it) {
        int k  = (t >> 5) + it * 8;
        int nl = t & 31;
        lbuf[k][nl] = W[(size_t)k * E + n0 + nl];
    }
    __syncthreads();
    for (int idx = t; idx < 32 * 136; idx += 256) {
        int nl = idx / 136, k = idx - nl * 136;
        float v = (k < 128) ? lbuf[k][nl] : 0.0f;
        WT[(size_t)(n0 + nl) * 136 + k] = f2bf_bits(v);
    }
}

// ---------------------------------------------------------------------------
// Kernel 2 (1024 blocks x 256):
//   blocks 0..767  : MFMA GEMM  V = [z; z_grid] @ Wv (bf16) + SC = X @ A
//   blocks 768..1023: per-point binning + x_grid passthrough copy
//     (independent of GEMM; hidden behind it. counts pre-zeroed by k_prep.)
// GEMM: WT1 image staged by linear float4 copy; 4 waves x MT=2 = 128 rows/blk.
// Layouts (HW-verified): A-frag m=lane&15, k=kq*32+q*8+j; B-frag n=lane&15
// same k; C/D col=lane&15, row=q*4+r.
// ---------------------------------------------------------------------------
__device__ __forceinline__ bf16x8 load_afrag_f32(const float* __restrict__ X,
                                                 int row, int kq, int q) {
    const float4* xr = (const float4*)(X + (size_t)row * E);
    float4 lo = xr[kq * 8 + q * 2];
    float4 hi = xr[kq * 8 + q * 2 + 1];
    union { unsigned u4[4]; bf16x8 v; } cv;
    cv.u4[0] = pack_bf2(lo.x, lo.y);
    cv.u4[1] = pack_bf2(lo.z, lo.w);
    cv.u4[2] = pack_bf2(hi.x, hi.y);
    cv.u4[3] = pack_bf2(hi.z, hi.w);
    return cv.v;
}

__global__ void __launch_bounds__(256)
k_main(const float* __restrict__ x,
       const float* __restrict__ x_grid,
       const float* __restrict__ Xz,
       const float* __restrict__ Xg,
       const unsigned short* __restrict__ WT1g,
       int* __restrict__ counts,
       int* __restrict__ slots,
       unsigned short* __restrict__ V,
       float* __restrict__ SC,
       float* __restrict__ out_xgrid) {
    __shared__ unsigned short W_t[20480];    // 40960 B

    const int t = threadIdx.x;

    if (blockIdx.x >= 768) {                 // ---- binning + x_grid copy
        int i = (blockIdx.x - 768) * 256 + t;   // 0..65535
        out_xgrid[i] = x_grid[i];
        int b = i >> 13;
        float x0 = x[(size_t)i * 2 + 0];
        float x1 = x[(size_t)i * 2 + 1];
        int i0 = (int)rintf(x0 * 63.0f);     // RNE matches jnp.round
        int i1 = (int)rintf(x1 * 63.0f);
        i0 = min(max(i0, 0), 63);
        i1 = min(max(i1, 0), 63);
        int cell = b * S_CELLS + i0 * 64 + i1;
        int slot = atomicAdd(&counts[cell], 1);
        if (slot < MAXP) slots[(size_t)cell * MAXP + slot] = i & (NPTS - 1);
        return;
    }

    {   // linear stage of WT1 image (no transpose -> no conflicts)
        const float4* src = (const float4*)WT1g;
        float4* dst = (float4*)W_t;
        #pragma unroll
        for (int it = 0; it < 10; ++it) dst[t + it * 256] = src[t + it * 256];
    }
    __syncthreads();

    const int lane = t & 63;
    const int wv   = t >> 6;
    const int cn   = lane & 15;
    const int q    = lane >> 4;

    const int grow0 = blockIdx.x * 128;
    const float* Xsrc;
    int srow;
    if (blockIdx.x < 512) { Xsrc = Xz; srow = grow0; }
    else                  { Xsrc = Xg; srow = grow0 - NPT_ROWS; }

    f32x4 acc[2][9];
    #pragma unroll
    for (int mt = 0; mt < 2; ++mt)
        #pragma unroll
        for (int nt = 0; nt < 9; ++nt)
            acc[mt][nt] = f32x4{0.0f, 0.0f, 0.0f, 0.0f};

    #pragma unroll
    for (int kq = 0; kq < 4; ++kq) {
        bf16x8 a[2];
        #pragma unroll
        for (int mt = 0; mt < 2; ++mt)
            a[mt] = load_afrag_f32(Xsrc, srow + wv * 32 + mt * 16 + cn, kq, q);
        #pragma unroll
        for (int nt = 0; nt < 9; ++nt) {
            const bf16x8 b = *(const bf16x8*)&W_t[(size_t)(nt * 16 + cn) * 136 + kq * 32 + q * 8];
            #pragma unroll
            for (int mt = 0; mt < 2; ++mt)
                acc[mt][nt] = __builtin_amdgcn_mfma_f32_16x16x32_bf16(
                    a[mt], b, acc[mt][nt], 0, 0, 0);
        }
    }

    #pragma unroll
    for (int mt = 0; mt < 2; ++mt) {
        const int rb = grow0 + wv * 32 + mt * 16 + q * 4;
        #pragma unroll
        for (int nt = 0; nt < 8; ++nt)
            #pragma unroll
            for (int r = 0; r < 4; ++r)
                V[(size_t)(rb + r) * E + nt * 16 + cn] = f2bf_rta(acc[mt][nt][r]);
        if (cn < 8) {
            #pragma unroll
            for (int r = 0; r < 4; ++r)
                SC[(size_t)(rb + r) * NHEADS + cn] = acc[mt][8][r];
        }
    }
}

// ---------------------------------------------------------------------------
// Kernel 3 (2048 blocks x 1024): fused attention + Wo projection.
//   Block = 16 cells, 16 waves; wave wv gathers cell cb+wv (1 cell/wave ->
//   minimal serial depth). Lane owns cols {2l,2l+1} (head h=l>>3 -> one
//   softmax state, packed uint V loads). Result -> X_s[wv] (bf16,
//   A-frag-ready). Phase 2: waves 0..7 hold Wo B-frags for nt=wv in
//   REGISTERS (preloaded, coalesced) -> 4 MFMAs each; no Wo LDS staging.
// LDS: 4352 B only.
// ---------------------------------------------------------------------------
__global__ void __launch_bounds__(1024)
k_attn_proj(const int* __restrict__ counts,
            const int* __restrict__ slots,
            const float* __restrict__ SC,
            const unsigned short* __restrict__ Vg,
            const unsigned short* __restrict__ WT2g,
            float* __restrict__ zg) {
    __shared__ __align__(16) unsigned short X_s[16][136];

    const int t    = threadIdx.x;
    const int lane = t & 63;
    const int wv   = t >> 6;                 // 0..15
    const int cb   = blockIdx.x * 16;
    const int b    = cb >> 12;
    const int base = b * NPTS;
    const int cn   = lane & 15;
    const int q    = lane >> 4;

    // preload Wo B-fragments (nt = wv for waves 0..7) — independent of phase 1
    bf16x8 bfr[4];
    if (wv < 8) {
        #pragma unroll
        for (int kq = 0; kq < 4; ++kq)
            bfr[kq] = *(const bf16x8*)&WT2g[(size_t)(wv * 16 + cn) * 136 + kq * 32 + q * 8];
    }

    // ---- phase 1: gather + online softmax for cell cb+wv
    const int cell = cb + wv;
    const int m    = min(counts[cell], MAXP);          // wave-uniform broadcast
    int sl = (lane < MAXP) ? slots[(size_t)cell * MAXP + lane] : 0;
    const int h = lane >> 3;

    size_t r0 = (size_t)(NPT_ROWS + cell);
    float mm = SC[r0 * NHEADS + h];
    float ss = 1.0f;
    unsigned v0 = *(const unsigned*)(Vg + r0 * E + 2 * lane);
    float o0 = bf2f((unsigned short)v0);
    float o1 = bf2f((unsigned short)(v0 >> 16));

    for (int t0 = 0; t0 < m; t0 += 4) {
        float av[4], p0[4], p1[4];
        #pragma unroll
        for (int j = 0; j < 4; ++j) {
            int pt = __shfl(sl, t0 + j, 64);
            bool val = (t0 + j) < m;
            pt = val ? pt : 0;               // slots beyond m are garbage
            size_t r = (size_t)(base + pt);
            float sa = SC[r * NHEADS + h];
            av[j] = val ? sa : -1e30f;       // masked -> e=0, alpha=1: exact no-op
            unsigned vv = *(const unsigned*)(Vg + r * E + 2 * lane);
            p0[j] = bf2f((unsigned short)vv);
            p1[j] = bf2f((unsigned short)(vv >> 16));
        }
        #pragma unroll
        for (int j = 0; j < 4; ++j) {
            float nm = fmaxf(mm, av[j]);
            float e  = __expf(av[j] - nm);
            float al = __expf(mm - nm);
            ss = ss * al + e;
            o0 = o0 * al + e * p0[j];
            o1 = o1 * al + e * p1[j];
            mm = nm;
        }
    }
    float inv = 1.0f / ss;
    *(unsigned*)&X_s[wv][2 * lane] = pack_bf2(o0 * inv, o1 * inv);
    __syncthreads();

    // ---- phase 2: zg[cb..cb+15][:] = X_s @ Wo  (wave wv -> col tile nt=wv)
    if (wv < 8) {
        f32x4 acc = f32x4{0.0f, 0.0f, 0.0f, 0.0f};
        #pragma unroll
        for (int kq = 0; kq < 4; ++kq) {
            bf16x8 a = *(const bf16x8*)&X_s[cn][kq * 32 + q * 8];
            acc = __builtin_amdgcn_mfma_f32_16x16x32_bf16(a, bfr[kq], acc, 0, 0, 0);
        }
        #pragma unroll
        for (int r = 0; r < 4; ++r)
            zg[(size_t)(cb + q * 4 + r) * E + wv * 16 + cn] = acc[r];
    }
}

// ---------------------------------------------------------------------------
extern "C" void kernel_launch(void* const* d_in, const int* in_sizes, int n_in,
                              void* d_out, int out_size, void* d_ws, size_t ws_size,
                              hipStream_t stream) {
    const float* x      = (const float*)d_in[0];
    const float* z      = (const float*)d_in[1];
    const float* x_grid = (const float*)d_in[2];
    const float* z_grid = (const float*)d_in[3];
    const float* latent = (const float*)d_in[4];
    const float* Wq     = (const float*)d_in[5];
    const float* Wk     = (const float*)d_in[6];
    const float* Wv     = (const float*)d_in[7];
    const float* Wo     = (const float*)d_in[8];

    char* ws = (char*)d_ws;
    int*            counts = (int*)(ws + WS_COUNTS);
    int*            slots  = (int*)(ws + WS_SLOTS);
    unsigned short* WT1    = (unsigned short*)(ws + WS_WT1);
    unsigned short* WT2    = (unsigned short*)(ws + WS_WT2);
    float*          SC     = (float*)(ws + WS_SC);
    unsigned short* V      = (unsigned short*)(ws + WS_V);

    float* out_xgrid = (float*)d_out;                  // 65536 floats
    float* zg        = (float*)d_out + NB * NPTS;      // 32768*128 floats

    k_prep<<<9, 256, 0, stream>>>(latent, Wq, Wk, Wv, Wo, counts, WT1, WT2);

    k_main<<<1024, 256, 0, stream>>>(x, x_grid, z, z_grid, WT1,
                                     counts, slots, V, SC, out_xgrid);

    k_attn_proj<<<2048, 1024, 0, stream>>>(counts, slots, SC, V, WT2, zg);
}